// Round 12
// baseline (679.447 us; speedup 1.0000x reference)
//
#include <hip/hip_runtime.h>

// Problem constants
#define NB 8
#define NS 256
#define ND 64
#define NV 8192
#define CH 16       // s-chunk per bilinear block (R7-proven)
#define NCHUNK 2176 // sum over t of (t/16 + 1)

typedef float f32x4 __attribute__((ext_vector_type(4)));
typedef short s16x4 __attribute__((ext_vector_type(4)));
typedef short s16x8 __attribute__((ext_vector_type(8)));

__device__ __forceinline__ short f2bf(float x) {
    union { float f; unsigned u; } v; v.f = x;
    unsigned u = v.u + 0x7FFFu + ((v.u >> 16) & 1u);  // RNE
    return (short)(u >> 16);
}

__device__ __forceinline__ f32x4 ntld(const float* p) {
    return __builtin_nontemporal_load(reinterpret_cast<const f32x4*>(p));
}

// h[b,s,d] = embed[x[b,s], d]; y = 0; cnt = 0; eb = bf16(embed)
// (512 blocks x 256 threads; each thread also casts 4 embed floats)
__global__ __launch_bounds__(256) void k_init(const int* __restrict__ x,
                                              const float* __restrict__ embed,
                                              float* __restrict__ h,
                                              float* __restrict__ y,
                                              short* __restrict__ eb,
                                              int* __restrict__ cnt) {
    int tid = blockIdx.x * 256 + threadIdx.x;
    int bs = tid >> 6;
    int d  = tid & 63;
    h[tid] = embed[(size_t)x[bs] * ND + d];
    y[tid] = 0.f;
    if (tid < NS) cnt[tid] = 0;
    // cast 4 floats -> bf16
    f32x4 v = *reinterpret_cast<const f32x4*>(embed + (size_t)tid * 4);
    s16x4 o;
    o.x = f2bf(v.x); o.y = f2bf(v.y); o.z = f2bf(v.z); o.w = f2bf(v.w);
    *reinterpret_cast<s16x4*>(eb + (size_t)tid * 4) = o;
}

// Fused: y[b,t,:] accumulation (triangular LJF, nt K-stream, 2-deep prefetch)
// + per-t completion counter; the LAST chunk-block of each t projects
// y[.,t,:] onto the vocabulary via bf16 MFMA and writes out[b*S+t, :].
__global__ __launch_bounds__(256) void k_bilinear(const float* __restrict__ h,
                                                  const float* __restrict__ K,
                                                  float* __restrict__ y,
                                                  const short* __restrict__ eb,
                                                  int* __restrict__ cnt,
                                                  float* __restrict__ out) {
    int L = (NCHUNK - 1) - (int)blockIdx.x;
    int g = 0;
    while (8 * (g + 1) * (g + 2) <= L) g++;       // group g = t>>4
    int rem = L - 8 * g * (g + 1);
    int tq  = rem / (g + 1);
    int t   = 16 * g + tq;
    int c   = rem - tq * (g + 1);
    int s0  = c * CH;
    int ns  = min(t + 1 - s0, CH);

    int ot = threadIdx.x & 15;   // o-quad index
    int dg = threadIdx.x >> 4;   // d-group 0..15
    int o4 = ot * 4;
    int db = dg * 4;

    // K prefetch first (no smem dependency): 2 slices in flight
    const float* Kp = K + (size_t)t * NS * ND * ND + (size_t)s0 * ND * ND
                        + db * ND + o4;
    f32x4 a0 = ntld(Kp);
    f32x4 a1 = ntld(Kp + ND);
    f32x4 a2 = ntld(Kp + 2 * ND);
    f32x4 a3 = ntld(Kp + 3 * ND);
    f32x4 b0 = a0, b1 = a1, b2 = a2, b3 = a3;
    if (ns > 1) {
        const float* K1 = Kp + (ND * ND);
        b0 = ntld(K1);
        b1 = ntld(K1 + ND);
        b2 = ntld(K1 + 2 * ND);
        b3 = ntld(K1 + 3 * ND);
    }

    __shared__ float smem[NB * CH * ND]; // 32 KB; reused for reduction + flag

    for (int i = threadIdx.x; i < NB * CH * ND; i += 256) {
        int b    = i >> 10;
        int rem2 = i & 1023;
        smem[i] = h[((size_t)b * NS + s0) * ND + rem2];
    }
    __syncthreads();

    f32x4 acc[NB];
#pragma unroll
    for (int b = 0; b < NB; b++) acc[b] = (f32x4)(0.f);

    for (int si = 0; si < ns; si++) {
        f32x4 m0 = b0, m1 = b1, m2 = b2, m3 = b3;
        if (si + 2 < ns) {
            const float* Kn = Kp + (size_t)(si + 2) * (ND * ND);
            m0 = ntld(Kn);
            m1 = ntld(Kn + ND);
            m2 = ntld(Kn + 2 * ND);
            m3 = ntld(Kn + 3 * ND);
        }
#pragma unroll
        for (int b = 0; b < NB; b++) {
            const float* hb = smem + b * (CH * ND) + si * ND + db;
            acc[b] += hb[0] * a0;
            acc[b] += hb[1] * a1;
            acc[b] += hb[2] * a2;
            acc[b] += hb[3] * a3;
        }
        a0 = b0; a1 = b1; a2 = b2; a3 = b3;
        b0 = m0; b1 = m1; b2 = m2; b3 = m3;
    }
    __syncthreads();

    f32x4* red = reinterpret_cast<f32x4*>(smem);
#pragma unroll
    for (int b = 0; b < NB; b++) red[(dg * NB + b) * 16 + ot] = acc[b];
    __syncthreads();

    if (threadIdx.x < 128) {
        int b = threadIdx.x >> 4;
        int o = threadIdx.x & 15;
        f32x4 s = (f32x4)(0.f);
#pragma unroll
        for (int gg = 0; gg < 16; gg++)
            s += red[(gg * NB + b) * 16 + o];
        float* yp = y + ((size_t)b * NS + t) * ND + o * 4;
        atomicAdd(yp + 0, s.x);
        atomicAdd(yp + 1, s.y);
        atomicAdd(yp + 2, s.z);
        atomicAdd(yp + 3, s.w);
    }
    __syncthreads();   // all y-atomics of this block drained

    int* flag = reinterpret_cast<int*>(smem);  // red no longer needed
    if (threadIdx.x == 0) {
        __threadfence();                        // release: y-atomics before cnt
        int old = atomicAdd(&cnt[t], 1);
        flag[0] = (old == (t >> 4)) ? 1 : 0;    // last of (t>>4)+1 chunks?
    }
    __syncthreads();
    if (!flag[0]) return;

    // ---- fused logits for this t: out[b*S+t, :] for b=0..7 ----
    __threadfence();                            // acquire side
    int wave = threadIdx.x >> 6;
    int lane = threadIdx.x & 63;
    int m    = lane & 15;
    int kg   = lane >> 4;
    int brow = min(m, 7);                       // rows 8..15 computed, discarded

    const float* ya = y + ((size_t)brow * NS + t) * ND + kg * 8;
    float av[8], av2[8];
#pragma unroll
    for (int j = 0; j < 8; j++)
        av[j] = __hip_atomic_load(ya + j, __ATOMIC_RELAXED, __HIP_MEMORY_SCOPE_AGENT);
#pragma unroll
    for (int j = 0; j < 8; j++)
        av2[j] = __hip_atomic_load(ya + 32 + j, __ATOMIC_RELAXED, __HIP_MEMORY_SCOPE_AGENT);
    s16x8 fa0, fa1;
#pragma unroll
    for (int j = 0; j < 8; j++) { fa0[j] = f2bf(av[j]); fa1[j] = f2bf(av2[j]); }

    for (int tile = 0; tile < 128; tile++) {
        int v0 = wave * 2048 + tile * 16;
        const short* erow = eb + (size_t)(v0 + m) * ND + kg * 8;
        s16x8 eb0 = *reinterpret_cast<const s16x8*>(erow);
        s16x8 eb1 = *reinterpret_cast<const s16x8*>(erow + 32);
        f32x4 cacc = (f32x4)(0.f);
        cacc = __builtin_amdgcn_mfma_f32_16x16x32_bf16(fa0, eb0, cacc, 0, 0, 0);
        cacc = __builtin_amdgcn_mfma_f32_16x16x32_bf16(fa1, eb1, cacc, 0, 0, 0);
        if (kg < 2) {
#pragma unroll
            for (int r = 0; r < 4; r++) {
                int row = kg * 4 + r;           // b = 0..7
                __builtin_nontemporal_store(cacc[r],
                    out + ((size_t)row * NS + t) * NV + v0 + m);
            }
        }
    }
}

extern "C" void kernel_launch(void* const* d_in, const int* in_sizes, int n_in,
                              void* d_out, int out_size, void* d_ws, size_t ws_size,
                              hipStream_t stream) {
    const int*   x     = (const int*)d_in[0];
    const float* embed = (const float*)d_in[1];
    const float* K     = (const float*)d_in[2];
    float* out = (float*)d_out;

    float* h  = (float*)d_ws;               // 131072 f32 (512 KB)
    float* y  = h + NB * NS * ND;           // 131072 f32 (512 KB)
    short* eb = (short*)(y + NB * NS * ND); // 524288 bf16 (1 MB)
    int*  cnt = (int*)(eb + (size_t)NV * ND); // 256 ints

    k_init<<<dim3(512), 256, 0, stream>>>(x, embed, h, y, eb, cnt);
    k_bilinear<<<dim3(NCHUNK), 256, 0, stream>>>(h, K, y, eb, cnt, out);
}

// Round 13
// 326.131 us; speedup vs baseline: 2.0834x; 2.0834x over previous
//
#include <hip/hip_runtime.h>

// Problem constants
#define NB 8
#define NS 256
#define ND 64
#define NV 8192
#define CH 16       // s-chunk per bilinear block (R7-proven)
#define NCHUNK 2176 // sum over t of (t/16 + 1)

typedef float f32x4 __attribute__((ext_vector_type(4)));
typedef short s16x4 __attribute__((ext_vector_type(4)));
typedef short s16x8 __attribute__((ext_vector_type(8)));

__device__ __forceinline__ short f2bf(float x) {
    union { float f; unsigned u; } v; v.f = x;
    unsigned u = v.u + 0x7FFFu + ((v.u >> 16) & 1u);  // RNE
    return (short)(u >> 16);
}

__device__ __forceinline__ f32x4 ntld(const float* p) {
    return __builtin_nontemporal_load(reinterpret_cast<const f32x4*>(p));
}

// h[b,s,d] = embed[x[b,s], d]; y = 0; cnt = 0; eb = bf16(embed)
__global__ __launch_bounds__(256) void k_init(const int* __restrict__ x,
                                              const float* __restrict__ embed,
                                              float* __restrict__ h,
                                              float* __restrict__ y,
                                              short* __restrict__ eb,
                                              int* __restrict__ cnt) {
    int tid = blockIdx.x * 256 + threadIdx.x;
    int bs = tid >> 6;
    int d  = tid & 63;
    h[tid] = embed[(size_t)x[bs] * ND + d];
    y[tid] = 0.f;
    if (tid < NS) cnt[tid] = 0;
    f32x4 v = *reinterpret_cast<const f32x4*>(embed + (size_t)tid * 4);
    s16x4 o;
    o.x = f2bf(v.x); o.y = f2bf(v.y); o.z = f2bf(v.z); o.w = f2bf(v.w);
    *reinterpret_cast<s16x4*>(eb + (size_t)tid * 4) = o;
}

// Fused bilinear + per-t-completion logits. R13: NO __threadfence —
// y-atomics complete (vmcnt drain at __syncthreads) before the cnt atomic;
// readers use agent-scope atomic loads at the coherence point.
__global__ __launch_bounds__(256) void k_bilinear(const float* __restrict__ h,
                                                  const float* __restrict__ K,
                                                  float* __restrict__ y,
                                                  const short* __restrict__ eb,
                                                  int* __restrict__ cnt,
                                                  float* __restrict__ out) {
    int L = (NCHUNK - 1) - (int)blockIdx.x;
    int g = 0;
    while (8 * (g + 1) * (g + 2) <= L) g++;       // group g = t>>4
    int rem = L - 8 * g * (g + 1);
    int tq  = rem / (g + 1);
    int t   = 16 * g + tq;
    int c   = rem - tq * (g + 1);
    int s0  = c * CH;
    int ns  = min(t + 1 - s0, CH);

    int ot = threadIdx.x & 15;   // o-quad index
    int dg = threadIdx.x >> 4;   // d-group 0..15
    int o4 = ot * 4;
    int db = dg * 4;

    // K prefetch first (no smem dependency): 2 slices in flight
    const float* Kp = K + (size_t)t * NS * ND * ND + (size_t)s0 * ND * ND
                        + db * ND + o4;
    f32x4 a0 = ntld(Kp);
    f32x4 a1 = ntld(Kp + ND);
    f32x4 a2 = ntld(Kp + 2 * ND);
    f32x4 a3 = ntld(Kp + 3 * ND);
    f32x4 b0 = a0, b1 = a1, b2 = a2, b3 = a3;
    if (ns > 1) {
        const float* K1 = Kp + (ND * ND);
        b0 = ntld(K1);
        b1 = ntld(K1 + ND);
        b2 = ntld(K1 + 2 * ND);
        b3 = ntld(K1 + 3 * ND);
    }

    __shared__ float smem[NB * CH * ND]; // 32 KB; reused for reduction + flag

    for (int i = threadIdx.x; i < NB * CH * ND; i += 256) {
        int b    = i >> 10;
        int rem2 = i & 1023;
        smem[i] = h[((size_t)b * NS + s0) * ND + rem2];
    }
    __syncthreads();

    f32x4 acc[NB];
#pragma unroll
    for (int b = 0; b < NB; b++) acc[b] = (f32x4)(0.f);

    for (int si = 0; si < ns; si++) {
        f32x4 m0 = b0, m1 = b1, m2 = b2, m3 = b3;
        if (si + 2 < ns) {
            const float* Kn = Kp + (size_t)(si + 2) * (ND * ND);
            m0 = ntld(Kn);
            m1 = ntld(Kn + ND);
            m2 = ntld(Kn + 2 * ND);
            m3 = ntld(Kn + 3 * ND);
        }
#pragma unroll
        for (int b = 0; b < NB; b++) {
            const float* hb = smem + b * (CH * ND) + si * ND + db;
            acc[b] += hb[0] * a0;
            acc[b] += hb[1] * a1;
            acc[b] += hb[2] * a2;
            acc[b] += hb[3] * a3;
        }
        a0 = b0; a1 = b1; a2 = b2; a3 = b3;
        b0 = m0; b1 = m1; b2 = m2; b3 = m3;
    }
    __syncthreads();

    f32x4* red = reinterpret_cast<f32x4*>(smem);
#pragma unroll
    for (int b = 0; b < NB; b++) red[(dg * NB + b) * 16 + ot] = acc[b];
    __syncthreads();

    if (threadIdx.x < 128) {
        int b = threadIdx.x >> 4;
        int o = threadIdx.x & 15;
        f32x4 s = (f32x4)(0.f);
#pragma unroll
        for (int gg = 0; gg < 16; gg++)
            s += red[(gg * NB + b) * 16 + o];
        float* yp = y + ((size_t)b * NS + t) * ND + o * 4;
        atomicAdd(yp + 0, s.x);
        atomicAdd(yp + 1, s.y);
        atomicAdd(yp + 2, s.z);
        atomicAdd(yp + 3, s.w);
    }
    __syncthreads();   // vmcnt drain: this block's y-atomics are complete

    int* flag = reinterpret_cast<int*>(smem);  // red no longer needed
    if (threadIdx.x == 0) {
        int old = atomicAdd(&cnt[t], 1);
        flag[0] = (old == (t >> 4)) ? 1 : 0;    // last of (t>>4)+1 chunks?
    }
    __syncthreads();
    if (!flag[0]) return;

    // ---- fused logits for this t: out[b*S+t, :] for b=0..7 ----
    int wave = threadIdx.x >> 6;
    int lane = threadIdx.x & 63;
    int m    = lane & 15;
    int kg   = lane >> 4;
    int brow = min(m, 7);                       // rows 8..15 computed, discarded

    const float* ya = y + ((size_t)brow * NS + t) * ND + kg * 8;
    float av[8], av2[8];
#pragma unroll
    for (int j = 0; j < 8; j++)
        av[j] = __hip_atomic_load(ya + j, __ATOMIC_RELAXED, __HIP_MEMORY_SCOPE_AGENT);
#pragma unroll
    for (int j = 0; j < 8; j++)
        av2[j] = __hip_atomic_load(ya + 32 + j, __ATOMIC_RELAXED, __HIP_MEMORY_SCOPE_AGENT);
    s16x8 fa0, fa1;
#pragma unroll
    for (int j = 0; j < 8; j++) { fa0[j] = f2bf(av[j]); fa1[j] = f2bf(av2[j]); }

    for (int tile = 0; tile < 128; tile++) {
        int v0 = wave * 2048 + tile * 16;
        const short* erow = eb + (size_t)(v0 + m) * ND + kg * 8;
        s16x8 eb0 = *reinterpret_cast<const s16x8*>(erow);
        s16x8 eb1 = *reinterpret_cast<const s16x8*>(erow + 32);
        f32x4 cacc = (f32x4)(0.f);
        cacc = __builtin_amdgcn_mfma_f32_16x16x32_bf16(fa0, eb0, cacc, 0, 0, 0);
        cacc = __builtin_amdgcn_mfma_f32_16x16x32_bf16(fa1, eb1, cacc, 0, 0, 0);
        if (kg < 2) {
#pragma unroll
            for (int r = 0; r < 4; r++) {
                int row = kg * 4 + r;           // b = 0..7
                __builtin_nontemporal_store(cacc[r],
                    out + ((size_t)row * NS + t) * NV + v0 + m);
            }
        }
    }
}

extern "C" void kernel_launch(void* const* d_in, const int* in_sizes, int n_in,
                              void* d_out, int out_size, void* d_ws, size_t ws_size,
                              hipStream_t stream) {
    const int*   x     = (const int*)d_in[0];
    const float* embed = (const float*)d_in[1];
    const float* K     = (const float*)d_in[2];
    float* out = (float*)d_out;

    float* h  = (float*)d_ws;               // 131072 f32 (512 KB)
    float* y  = h + NB * NS * ND;           // 131072 f32 (512 KB)
    short* eb = (short*)(y + NB * NS * ND); // 524288 bf16 (1 MB)
    int*  cnt = (int*)(eb + (size_t)NV * ND); // 256 ints

    k_init<<<dim3(512), 256, 0, stream>>>(x, embed, h, y, eb, cnt);
    k_bilinear<<<dim3(NCHUNK), 256, 0, stream>>>(h, K, y, eb, cnt, out);
}

// Round 14
// 136.964 us; speedup vs baseline: 4.9608x; 2.3811x over previous
//
#include <hip/hip_runtime.h>

// Problem constants
#define NB 8
#define NS 256
#define ND 64
#define NV 8192
#define CH 16       // s-chunk per bilinear block (R7-proven)
#define NCHUNK 2176 // sum over t of (t/16 + 1)

typedef float f32x4 __attribute__((ext_vector_type(4)));
typedef short s16x4 __attribute__((ext_vector_type(4)));
typedef short s16x8 __attribute__((ext_vector_type(8)));

__device__ __forceinline__ short f2bf(float x) {
    union { float f; unsigned u; } v; v.f = x;
    unsigned u = v.u + 0x7FFFu + ((v.u >> 16) & 1u);  // RNE
    return (short)(u >> 16);
}

__device__ __forceinline__ s16x8 cvt8(f32x4 lo, f32x4 hi) {
    s16x8 r;
    r[0] = f2bf(lo.x); r[1] = f2bf(lo.y); r[2] = f2bf(lo.z); r[3] = f2bf(lo.w);
    r[4] = f2bf(hi.x); r[5] = f2bf(hi.y); r[6] = f2bf(hi.z); r[7] = f2bf(hi.w);
    return r;
}

__device__ __forceinline__ f32x4 ntld(const float* p) {
    return __builtin_nontemporal_load(reinterpret_cast<const f32x4*>(p));
}

// h[b,s,d] = embed[x[b,s], d]; y = 0; eb = bf16(embed)   (512 blocks)
__global__ __launch_bounds__(256) void k_init(const int* __restrict__ x,
                                              const float* __restrict__ embed,
                                              float* __restrict__ h,
                                              float* __restrict__ y,
                                              short* __restrict__ eb) {
    int tid = blockIdx.x * 256 + threadIdx.x;
    int bs = tid >> 6;
    int d  = tid & 63;
    h[tid] = embed[(size_t)x[bs] * ND + d];
    y[tid] = 0.f;
    f32x4 v = *reinterpret_cast<const f32x4*>(embed + (size_t)tid * 4);
    s16x4 o;
    o.x = f2bf(v.x); o.y = f2bf(v.y); o.z = f2bf(v.z); o.w = f2bf(v.w);
    *reinterpret_cast<s16x4*>(eb + (size_t)tid * 4) = o;
}

// y[b,t,o] += sum_{s in chunk, s<=t} sum_d h[b,s,d] * K[t,s,d,o]
// Triangular LJF launch; CH=16; nt K-stream; 2-deep register prefetch,
// prefetch hoisted above the h-stage. (R11-proven, best = 139.4 us)
__global__ __launch_bounds__(256) void k_bilinear(const float* __restrict__ h,
                                                  const float* __restrict__ K,
                                                  float* __restrict__ y) {
    int L = (NCHUNK - 1) - (int)blockIdx.x;
    int g = 0;
    while (8 * (g + 1) * (g + 2) <= L) g++;       // group g = t>>4
    int rem = L - 8 * g * (g + 1);
    int tq  = rem / (g + 1);
    int t   = 16 * g + tq;
    int c   = rem - tq * (g + 1);
    int s0  = c * CH;
    int ns  = min(t + 1 - s0, CH);

    int ot = threadIdx.x & 15;   // o-quad index
    int dg = threadIdx.x >> 4;   // d-group 0..15
    int o4 = ot * 4;
    int db = dg * 4;

    // K prefetch first (no smem dependency): 2 slices in flight
    const float* Kp = K + (size_t)t * NS * ND * ND + (size_t)s0 * ND * ND
                        + db * ND + o4;
    f32x4 a0 = ntld(Kp);
    f32x4 a1 = ntld(Kp + ND);
    f32x4 a2 = ntld(Kp + 2 * ND);
    f32x4 a3 = ntld(Kp + 3 * ND);
    f32x4 b0 = a0, b1 = a1, b2 = a2, b3 = a3;
    if (ns > 1) {
        const float* K1 = Kp + (ND * ND);
        b0 = ntld(K1);
        b1 = ntld(K1 + ND);
        b2 = ntld(K1 + 2 * ND);
        b3 = ntld(K1 + 3 * ND);
    }

    __shared__ float smem[NB * CH * ND]; // 32 KB; reused for reduction

    for (int i = threadIdx.x; i < NB * CH * ND; i += 256) {
        int b    = i >> 10;
        int rem2 = i & 1023;
        smem[i] = h[((size_t)b * NS + s0) * ND + rem2];
    }
    __syncthreads();

    f32x4 acc[NB];
#pragma unroll
    for (int b = 0; b < NB; b++) acc[b] = (f32x4)(0.f);

    for (int si = 0; si < ns; si++) {
        f32x4 m0 = b0, m1 = b1, m2 = b2, m3 = b3;
        if (si + 2 < ns) {
            const float* Kn = Kp + (size_t)(si + 2) * (ND * ND);
            m0 = ntld(Kn);
            m1 = ntld(Kn + ND);
            m2 = ntld(Kn + 2 * ND);
            m3 = ntld(Kn + 3 * ND);
        }
#pragma unroll
        for (int b = 0; b < NB; b++) {
            const float* hb = smem + b * (CH * ND) + si * ND + db;
            acc[b] += hb[0] * a0;
            acc[b] += hb[1] * a1;
            acc[b] += hb[2] * a2;
            acc[b] += hb[3] * a3;
        }
        a0 = b0; a1 = b1; a2 = b2; a3 = b3;
        b0 = m0; b1 = m1; b2 = m2; b3 = m3;
    }
    __syncthreads();

    f32x4* red = reinterpret_cast<f32x4*>(smem);
#pragma unroll
    for (int b = 0; b < NB; b++) red[(dg * NB + b) * 16 + ot] = acc[b];
    __syncthreads();

    if (threadIdx.x < 128) {
        int b = threadIdx.x >> 4;
        int o = threadIdx.x & 15;
        f32x4 s = (f32x4)(0.f);
#pragma unroll
        for (int gg = 0; gg < 16; gg++)
            s += red[(gg * NB + b) * 16 + o];
        float* yp = y + ((size_t)b * NS + t) * ND + o * 4;
        atomicAdd(yp + 0, s.x);
        atomicAdd(yp + 1, s.y);
        atomicAdd(yp + 2, s.z);
        atomicAdd(yp + 3, s.w);
    }
}

// out[bt, v] = sum_o y[bt, o] * E[v, o]  via bf16 MFMA (16x16x32, K=o)
__global__ __launch_bounds__(256) void k_logits_mfma(const float* __restrict__ y,
                                                     const short* __restrict__ eb,
                                                     float* __restrict__ out) {
    int bt0  = blockIdx.x * 16;
    int wave = threadIdx.x >> 6;
    int lane = threadIdx.x & 63;
    int m    = lane & 15;      // A row / B col / D col
    int kg   = lane >> 4;      // k-group of 8
    int vb0  = blockIdx.y * 1024 + wave * 256;

    const float* yrow = y + (size_t)(bt0 + m) * ND + kg * 8;
    f32x4 p0 = *reinterpret_cast<const f32x4*>(yrow);
    f32x4 p1 = *reinterpret_cast<const f32x4*>(yrow + 4);
    f32x4 p2 = *reinterpret_cast<const f32x4*>(yrow + 32);
    f32x4 p3 = *reinterpret_cast<const f32x4*>(yrow + 36);
    s16x8 a0 = cvt8(p0, p1);
    s16x8 a1 = cvt8(p2, p3);

    for (int nt = 0; nt < 16; nt++) {
        int v0 = vb0 + nt * 16;
        const short* erow = eb + (size_t)(v0 + m) * ND + kg * 8;
        s16x8 b0 = *reinterpret_cast<const s16x8*>(erow);
        s16x8 b1 = *reinterpret_cast<const s16x8*>(erow + 32);
        f32x4 cacc = (f32x4)(0.f);
        cacc = __builtin_amdgcn_mfma_f32_16x16x32_bf16(a0, b0, cacc, 0, 0, 0);
        cacc = __builtin_amdgcn_mfma_f32_16x16x32_bf16(a1, b1, cacc, 0, 0, 0);
        float* op = out + (size_t)(bt0 + kg * 4) * NV + v0 + m;
#pragma unroll
        for (int r = 0; r < 4; r++)
            __builtin_nontemporal_store(cacc[r], op + (size_t)r * NV);
    }
}

extern "C" void kernel_launch(void* const* d_in, const int* in_sizes, int n_in,
                              void* d_out, int out_size, void* d_ws, size_t ws_size,
                              hipStream_t stream) {
    const int*   x     = (const int*)d_in[0];
    const float* embed = (const float*)d_in[1];
    const float* K     = (const float*)d_in[2];
    float* out = (float*)d_out;

    float* h  = (float*)d_ws;               // 131072 f32 (512 KB)
    float* y  = h + NB * NS * ND;           // 131072 f32 (512 KB)
    short* eb = (short*)(y + NB * NS * ND); // 524288 bf16 (1 MB)

    k_init<<<dim3(512), 256, 0, stream>>>(x, embed, h, y, eb);
    k_bilinear<<<dim3(NCHUNK), 256, 0, stream>>>(h, K, y);
    k_logits_mfma<<<dim3((NB * NS) / 16, NV / 1024), 256, 0, stream>>>(y, eb, out);
}